// Round 1
// baseline (740.341 us; speedup 1.0000x reference)
//
#include <hip/hip_runtime.h>

// PatchEmbedding: unfold(k=2, stride=1, pad=0) on (1,3,384,384) fp32,
// linear 12->768, + bias + positions. out[e][l] with l = p*383+q.
//
// Memory-bound: ~451 MB positions read + ~451 MB out write are mandatory.
// x (1.77 MB) is the only reused data -> keep it cached; stream pos/out
// with nontemporal (nt) accesses so they don't evict x from L2 or churn L3.
// Measured context: harness re-poison fills (~2x284 us) dominate dur_us;
// kernel dispatch itself is ~170 us vs ~143 us copy-roofline floor.

constexpr int IMG = 384;
constexpr int L1  = IMG - 1;        // 383
constexpr int L   = L1 * L1;        // 146689
constexpr int EMB = 768;
constexpr int PD  = 12;             // 3 * 2 * 2
constexpr int EPB = 16;             // embedding channels per block (grid.y)
constexpr int NG  = (L + 3) / 4;    // 36673 float4 groups along l

// e*L + l0 is only 4B-aligned (L odd) -> 16B access with 4B alignment.
// AMDGPU allows dword-aligned multi-dword vector memory ops; the aligned(4)
// typedef keeps the IR honest about it.
typedef float f4v __attribute__((ext_vector_type(4)));
typedef f4v uf4v __attribute__((aligned(4)));
struct __attribute__((packed, aligned(4))) f2u { float x, y; };

__global__ __launch_bounds__(256) void patch_embed_kernel(
    const float* __restrict__ x,
    const float* __restrict__ W,
    const float* __restrict__ b,
    const float* __restrict__ pos,
    float* __restrict__ out)
{
    const int g = blockIdx.x * blockDim.x + threadIdx.x;   // float4-group index
    if (g >= NG) return;
    const int l0    = g * 4;
    const int e0    = blockIdx.y * EPB;
    const int valid = min(4, L - l0);                      // 4 except last group (1)

    // Gather the 12 patch values for each of the 4 lanes. All hits in L1/L2
    // (x is 1.77 MB). d = c*4 + i*2 + j matches torch unfold channel order.
    // Adjacent columns (j=0,1) load as one dwordx2: 24 VMEM ops instead of 48.
    float patch[4][PD];
    #pragma unroll
    for (int lane = 0; lane < 4; ++lane) {
        int l = l0 + lane;
        if (l >= L) l = L - 1;                             // clamp; unused lanes
        const unsigned p = (unsigned)l / L1;
        const unsigned q = (unsigned)l - p * L1;
        const float* xp = x + p * IMG + q;
        #pragma unroll
        for (int c = 0; c < 3; ++c)
            #pragma unroll
            for (int i = 0; i < 2; ++i) {
                f2u v = *(const f2u*)(xp + c * IMG * IMG + i * IMG);
                patch[lane][c * 4 + i * 2 + 0] = v.x;
                patch[lane][c * 4 + i * 2 + 1] = v.y;
            }
    }

    // Loop over 16 embedding channels; W/b indices are wave-uniform -> s_load.
    #pragma unroll 4
    for (int ii = 0; ii < EPB; ++ii) {
        const int e = e0 + ii;
        float wreg[PD];
        #pragma unroll
        for (int d = 0; d < PD; ++d) wreg[d] = W[e * PD + d];
        const float bias = b[e];
        const size_t base = (size_t)e * L + (size_t)l0;

        float r[4];
        #pragma unroll
        for (int lane = 0; lane < 4; ++lane) {
            float acc = bias;
            #pragma unroll
            for (int d = 0; d < PD; ++d)
                acc = fmaf(wreg[d], patch[lane][d], acc);
            r[lane] = acc;
        }

        if (valid == 4) {
            // Streaming data: nontemporal so pos/out don't allocate/evict in
            // L2 (protects x residency) or thrash L3.
            uf4v p4 = __builtin_nontemporal_load((const uf4v*)(pos + base));
            uf4v o;
            o.x = r[0] + p4.x;
            o.y = r[1] + p4.y;
            o.z = r[2] + p4.z;
            o.w = r[3] + p4.w;
            __builtin_nontemporal_store(o, (uf4v*)(out + base));
        } else {
            for (int lane = 0; lane < valid; ++lane) {
                float pv = __builtin_nontemporal_load(pos + base + lane);
                __builtin_nontemporal_store(r[lane] + pv, out + base + lane);
            }
        }
    }
}

extern "C" void kernel_launch(void* const* d_in, const int* in_sizes, int n_in,
                              void* d_out, int out_size, void* d_ws, size_t ws_size,
                              hipStream_t stream) {
    const float* x   = (const float*)d_in[0];
    const float* W   = (const float*)d_in[1];
    const float* b   = (const float*)d_in[2];
    const float* pos = (const float*)d_in[3];
    float* out = (float*)d_out;

    dim3 block(256);
    dim3 grid((NG + 255) / 256, EMB / EPB);   // 144 x 48 = 6912 blocks
    patch_embed_kernel<<<grid, block, 0, stream>>>(x, W, b, pos, out);
}